// Round 10
// baseline (182.348 us; speedup 1.0000x reference)
//
#include <hip/hip_runtime.h>

typedef unsigned short u16;
typedef unsigned int u32;
typedef short short8 __attribute__((ext_vector_type(8)));
typedef short s16x4 __attribute__((ext_vector_type(4)));
typedef float f32x4 __attribute__((ext_vector_type(4)));

#define N_B 2
#define N_L 2048
#define N_D 1024
#define N_H 16
#define N_KVH 4
#define HDIM 64
#define WINDOW 1024

// log2(e) folded into Q so softmax can use exp2 directly
#define QSCALE (0.125f * 1.44269504088896f)

__device__ __forceinline__ u16 f2bf(float f) {
  unsigned u = __builtin_bit_cast(unsigned, f);
  u = u + 0x7fffu + ((u >> 16) & 1u);
  return (u16)(u >> 16);
}

// pack two f32 -> (bf16(hi)<<16)|bf16(lo), round-half-up, one v_perm
__device__ __forceinline__ u32 pk2bf(float lo, float hi) {
  u32 a = __builtin_bit_cast(u32, lo) + 0x8000u;
  u32 b = __builtin_bit_cast(u32, hi) + 0x8000u;
  return __builtin_amdgcn_perm(b, a, 0x07060302u);
}

// async global->LDS, 16B per lane. LDS dest must be wave-uniform base + lane*16.
__device__ __forceinline__ void gl2lds16(const u16* g, u16* l) {
  __builtin_amdgcn_global_load_lds((const __attribute__((address_space(1))) void*)g,
                                   (__attribute__((address_space(3))) void*)l, 16, 0, 0);
}

// K=16 bf16 MFMA (builtin name differs across ROCm versions)
__device__ __forceinline__ f32x4 mfma16(s16x4 a, s16x4 b, f32x4 c) {
#if __has_builtin(__builtin_amdgcn_mfma_f32_16x16x16_bf16)
  return __builtin_amdgcn_mfma_f32_16x16x16_bf16(a, b, c, 0, 0, 0);
#else
  return __builtin_amdgcn_mfma_f32_16x16x16bf16_1k(a, b, c, 0, 0, 0);
#endif
}

// ---------------- fused prep: convert x, transpose 4 weights, rope ----------------

__global__ __launch_bounds__(256) void prep_kernel(
    const float* __restrict__ x, const float* __restrict__ Wq, const float* __restrict__ Wk,
    const float* __restrict__ Wv, const float* __restrict__ Wo,
    u16* __restrict__ xb, u16* __restrict__ wqkvT, u16* __restrict__ woT,
    float* __restrict__ rc, float* __restrict__ rs) {
  __shared__ float tbuf[32][33];
  int bid = blockIdx.x, tid = threadIdx.x;
  if (bid < 1024) {  // x fp32 -> bf16, 16 elems/thread
    size_t base = ((size_t)bid * 256 + tid) * 16;
    u32 o[8];
#pragma unroll
    for (int j = 0; j < 4; j++) {
      float4 f = *(const float4*)&x[base + j * 4];
      o[2 * j] = pk2bf(f.x, f.y);
      o[2 * j + 1] = pk2bf(f.z, f.w);
    }
    *(uint4*)&xb[base] = *(uint4*)&o[0];
    *(uint4*)&xb[base + 8] = *(uint4*)&o[4];
  } else if (bid < 3584) {  // weight transposes [1024][srcN] -> [srcN][1024] bf16
    const float* src;
    u16* dst;
    int gx, t, shift;
    if (bid < 2048) { src = Wq; dst = wqkvT; gx = 32; shift = 5; t = bid - 1024; }
    else if (bid < 2304) { src = Wk; dst = wqkvT + 1024 * 1024; gx = 8; shift = 3; t = bid - 2048; }
    else if (bid < 2560) { src = Wv; dst = wqkvT + 1280 * 1024; gx = 8; shift = 3; t = bid - 2304; }
    else { src = Wo; dst = woT; gx = 32; shift = 5; t = bid - 2560; }
    int srcN = gx * 32;
    int n0 = (t & (gx - 1)) * 32, k0 = (t >> shift) * 32;
    int lx = tid & 31, ly = tid >> 5;
#pragma unroll
    for (int q = 0; q < 4; q++)
      tbuf[ly + 8 * q][lx] = src[(k0 + ly + 8 * q) * srcN + n0 + lx];
    __syncthreads();
#pragma unroll
    for (int q = 0; q < 4; q++)
      dst[(n0 + ly + 8 * q) * 1024 + k0 + lx] = f2bf(tbuf[lx][ly + 8 * q]);
  } else {  // rope tables, 2048*32
    int idx = (bid - 3584) * 256 + tid;
    int i = idx >> 5, j = idx & 31;
    float inv = powf(10000.0f, -(float)j * (1.0f / 32.0f));
    float ang = (float)i * inv;
    rc[idx] = cosf(ang);
    rs[idx] = sinf(ang);
  }
}

// ---------------- GEMM: C[M,N] = A[M,K=1024] * Bt[N,K=1024]^T ----------------
// 128x128 block, 4 waves 2x2 of 64x64, BK=64, XOR-swizzled LDS, double-buffered
// global_load_lds, single barrier per kt.
// MODE 0: qkv projection; RoPE epilogue; V stored transposed. Grid (12, 32).
// MODE 2: out projection, split-K over blockIdx.z, fp32 atomic add. Grid (8, 32, 2).

template <int MODE>
__global__ __launch_bounds__(256, 2) void gemm_kernel(
    const u16* __restrict__ A, const u16* __restrict__ Bt,
    u16* __restrict__ qo, u16* __restrict__ ko, u16* __restrict__ vo,
    float* __restrict__ fo, const float* __restrict__ rc, const float* __restrict__ rs) {
  __shared__ u16 smem[65536 / 2];  // [A0|A1|B0|B1] each 128x64 u16 (8192)
  int tid = threadIdx.x;
  int w = tid >> 6, lane = tid & 63, quad = lane >> 4, r = lane & 15;
  int rx = r & 7;
  int wm = w >> 1, wn = w & 1;
  int m0 = blockIdx.y * 128, n0 = blockIdx.x * 128;
  constexpr int NKT = (MODE == 2) ? 8 : 16;
  int koff = (MODE == 2) ? blockIdx.z * NKT : 0;

  f32x4 acc[4][4];
#pragma unroll
  for (int a_ = 0; a_ < 4; a_++)
#pragma unroll
    for (int b_ = 0; b_ < 4; b_++) acc[a_][b_] = {0.f, 0.f, 0.f, 0.f};

  auto stage = [&](int kt, int buf) {
    u16* a_s = smem + buf * 8192;
    u16* b_s = smem + 16384 + buf * 8192;
#pragma unroll
    for (int it = 0; it < 4; ++it) {
      int cc = it * 256 + tid;
      int row = cc >> 3, p = cc & 7, c = p ^ (row & 7);
      gl2lds16(&A[(size_t)(m0 + row) * 1024 + (koff + kt) * 64 + c * 8], &a_s[cc * 8]);
    }
#pragma unroll
    for (int it = 0; it < 4; ++it) {
      int cc = it * 256 + tid;
      int row = cc >> 3, p = cc & 7, c = p ^ (row & 7);
      gl2lds16(&Bt[(size_t)(n0 + row) * 1024 + (koff + kt) * 64 + c * 8], &b_s[cc * 8]);
    }
  };

  stage(0, 0);
  for (int kt = 0; kt < NKT; ++kt) {
    int buf = kt & 1;
    __syncthreads();  // single barrier per kt: drains this buf's staging
    if (kt + 1 < NKT) stage(kt + 1, buf ^ 1);
    u16* a_s = smem + buf * 8192;
    u16* b_s = smem + 16384 + buf * 8192;
#pragma unroll
    for (int ks = 0; ks < 2; ks++) {
      int pc = (ks * 4 + quad) ^ rx;
      short8 af[4], bfr[4];
#pragma unroll
      for (int tm = 0; tm < 4; tm++)
        af[tm] = *(const short8*)&a_s[(wm * 64 + tm * 16 + r) * 64 + pc * 8];
#pragma unroll
      for (int tn = 0; tn < 4; tn++)
        bfr[tn] = *(const short8*)&b_s[(wn * 64 + tn * 16 + r) * 64 + pc * 8];
#pragma unroll
      for (int tm = 0; tm < 4; tm++)
#pragma unroll
        for (int tn = 0; tn < 4; tn++)
          acc[tm][tn] = __builtin_amdgcn_mfma_f32_16x16x32_bf16(af[tm], bfr[tn], acc[tm][tn], 0, 0, 0);
    }
  }

  int nbase = n0 + wn * 64;  // 64-aligned, uniform per wave
  if constexpr (MODE == 0) {
    if (nbase < 1024) {  // Q + RoPE + QSCALE
      int h = nbase >> 6;
#pragma unroll
      for (int tm = 0; tm < 4; tm++) {
#pragma unroll
        for (int reg = 0; reg < 4; reg++) {
          int m = m0 + wm * 64 + tm * 16 + quad * 4 + reg;
          int b = m >> 11, i = m & 2047;
          size_t base = ((size_t)(b * N_H + h) * N_L + i) * HDIM;
#pragma unroll
          for (int tn = 0; tn < 2; tn++) {
            int dlo = tn * 16 + r;
            float c = rc[i * 32 + dlo], s = rs[i * 32 + dlo];
            float vlo = acc[tm][tn][reg], vhi = acc[tm][tn + 2][reg];
            qo[base + dlo] = f2bf((vlo * c - vhi * s) * QSCALE);
            qo[base + dlo + 32] = f2bf((vhi * c + vlo * s) * QSCALE);
          }
        }
      }
    } else if (nbase < 1280) {  // K + RoPE
      int h = (nbase - 1024) >> 6;
#pragma unroll
      for (int tm = 0; tm < 4; tm++) {
#pragma unroll
        for (int reg = 0; reg < 4; reg++) {
          int m = m0 + wm * 64 + tm * 16 + quad * 4 + reg;
          int b = m >> 11, i = m & 2047;
          size_t base = ((size_t)(b * N_KVH + h) * N_L + i) * HDIM;
#pragma unroll
          for (int tn = 0; tn < 2; tn++) {
            int dlo = tn * 16 + r;
            float c = rc[i * 32 + dlo], s = rs[i * 32 + dlo];
            float vlo = acc[tm][tn][reg], vhi = acc[tm][tn + 2][reg];
            ko[base + dlo] = f2bf(vlo * c - vhi * s);
            ko[base + dlo + 32] = f2bf(vhi * c + vlo * s);
          }
        }
      }
    } else {  // V: transpose bounce reusing staging LDS -> Vt[b][hkv][64][2048]
      __syncthreads();
      int hkv = (nbase - 1280) >> 6;
      int bb = (m0 + wm * 64) >> 11;
      int tbase = (m0 + wm * 64) & 2047;
      u16* myvs = smem + w * 4608;  // [64 d][64 tok] stride 72
#pragma unroll
      for (int tm = 0; tm < 4; tm++) {
#pragma unroll
        for (int tn = 0; tn < 4; tn++) {
          uint2 pk;
          pk.x = pk2bf(acc[tm][tn][0], acc[tm][tn][1]);
          pk.y = pk2bf(acc[tm][tn][2], acc[tm][tn][3]);
          *(uint2*)&myvs[(tn * 16 + r) * 72 + tm * 16 + quad * 4] = pk;
        }
      }
      __asm__ volatile("s_waitcnt lgkmcnt(0)" ::: "memory");
      u16* vtb = vo + (size_t)((bb * N_KVH + hkv) * 64) * 2048;
#pragma unroll
      for (int q2 = 0; q2 < 8; ++q2) {
        int flat = q2 * 64 + lane;
        int row = flat >> 3, part = flat & 7;
        uint4 val = *(uint4*)&myvs[row * 72 + part * 8];
        *(uint4*)&vtb[row * 2048 + tbase + part * 8] = val;
      }
    }
  } else {  // MODE 2: split-K atomic fp32 accumulate (2 addends -> deterministic)
#pragma unroll
    for (int tm = 0; tm < 4; tm++) {
#pragma unroll
      for (int reg = 0; reg < 4; reg++) {
        int m = m0 + wm * 64 + tm * 16 + quad * 4 + reg;
#pragma unroll
        for (int tn = 0; tn < 4; tn++)
          unsafeAtomicAdd(&fo[(size_t)m * 1024 + nbase + tn * 16 + r], acc[tm][tn][reg]);
      }
    }
  }
}

// ---------------- flash attention, sliding window, GQA ----------------
// Wave w owns keys [w*16,w*16+16) of each 64-key tile; Q (all 64 block-queries)
// lives in registers as B-fragments. S^T = K*Q^T via 16x16x32; its C-layout IS
// the K=16 B-operand layout, so P feeds mfma 16x16x16 PV straight from registers
// (no LDS round-trip). Per-wave partial O^T reduced cross-wave in the epilogue
// through the dead staging LDS. Fixed-max softmax (p = exp2(s), in-lane l).
// grid (32 qblocks reversed, 16 heads, 2 batch), 256 threads.

__global__ __launch_bounds__(256) void attn_kernel(
    const u16* __restrict__ Q, const u16* __restrict__ K,
    const u16* __restrict__ Vt, u16* __restrict__ O) {
  __shared__ __align__(16) u16 smem[16384];  // [k0|k1|v0|v1] 4096 u16 each; epilogue: f32 red[2][4][1024]
  __shared__ float l_s[256];
  int tid = threadIdx.x, w = tid >> 6, lane = tid & 63, quad = lane >> 4, r = lane & 15;
  int qb = 31 - blockIdx.x;  // long blocks first
  int h = blockIdx.y, b = blockIdx.z;
  int i0 = qb * 64;
  int hk = h >> 2;
  int rx = r & 7;

  // Q B-fragments for all 64 block queries: qf[tn][ks]
  const u16* qbase = Q + (size_t)((b * N_H + h) * N_L + i0) * HDIM;
  short8 qf[4][2];
#pragma unroll
  for (int tn = 0; tn < 4; tn++)
#pragma unroll
    for (int ks = 0; ks < 2; ks++)
      qf[tn][ks] = *(const short8*)&qbase[(size_t)(tn * 16 + r) * 64 + ks * 32 + quad * 8];

  const u16* kbase = K + (size_t)(b * N_KVH + hk) * N_L * HDIM;
  const u16* vtbase = Vt + (size_t)(b * N_KVH + hk) * HDIM * N_L;

  auto stage = [&](int jt, int buf) {
    u16* ksb = smem + buf * 4096;
    u16* vsb = smem + 8192 + buf * 4096;
#pragma unroll
    for (int it = 0; it < 2; ++it) {
      int cc = it * 256 + tid;
      int row = cc >> 3, p = cc & 7, c = p ^ (row & 7);
      gl2lds16(&kbase[(size_t)(jt * 64 + row) * 64 + c * 8], &ksb[cc * 8]);
    }
#pragma unroll
    for (int it = 0; it < 2; ++it) {
      int cc = it * 256 + tid;
      int row = cc >> 3, p = cc & 7, c = p ^ (row & 7);
      gl2lds16(&vtbase[(size_t)row * 2048 + jt * 64 + c * 8], &vsb[cc * 8]);
    }
  };

  float l_acc[4] = {0.f, 0.f, 0.f, 0.f};
  f32x4 o_acc[4][4];
#pragma unroll
  for (int tm = 0; tm < 4; tm++)
#pragma unroll
    for (int tn = 0; tn < 4; tn++) o_acc[tm][tn] = {0.f, 0.f, 0.f, 0.f};

  int jt0 = (i0 >= WINDOW) ? ((i0 - (WINDOW - 1)) >> 6) : 0;
  int nt = qb - jt0 + 1;

  stage(jt0, 0);

  for (int t = 0; t < nt; ++t) {
    int jt = jt0 + t, j0 = jt << 6, buf = t & 1;
    __syncthreads();  // drains vmcnt: buf's staging complete
    if (t + 1 < nt) stage(jt + 1, buf ^ 1);
    u16* ksb = smem + buf * 4096;
    u16* vsb = smem + 8192 + buf * 4096;

    // S^T[key][query]: A = K rows (wave's 16 keys), B = Q (64 queries)
    f32x4 s_acc[4];
#pragma unroll
    for (int tn = 0; tn < 4; tn++) s_acc[tn] = {0.f, 0.f, 0.f, 0.f};
#pragma unroll
    for (int ks = 0; ks < 2; ks++) {
      int pc = (ks * 4 + quad) ^ rx;
      short8 kf = *(const short8*)&ksb[(w * 16 + r) * 64 + pc * 8];
#pragma unroll
      for (int tn = 0; tn < 4; tn++)
        s_acc[tn] = __builtin_amdgcn_mfma_f32_16x16x32_bf16(kf, qf[tn][ks], s_acc[tn], 0, 0, 0);
    }

    // mask (wave-uniform interior test; per-element on edges)
    int jw = j0 + w * 16;
    bool interior = (jw + 15 <= i0) && ((i0 + 63 - jw) < WINDOW);
    if (!interior) {
#pragma unroll
      for (int tn = 0; tn < 4; tn++) {
#pragma unroll
        for (int reg = 0; reg < 4; reg++) {
          int j = jw + quad * 4 + reg;
          int i = i0 + tn * 16 + r;
          bool ok = (j <= i) && (i - j < WINDOW);
          if (!ok) s_acc[tn][reg] = -1e30f;  // exp2 -> 0
        }
      }
    }

    // p = exp2(s) in-register; C-layout == K=16 B-operand layout
    s16x4 pf[4];
#pragma unroll
    for (int tn = 0; tn < 4; tn++) {
      float e0 = __builtin_amdgcn_exp2f(s_acc[tn][0]);
      float e1 = __builtin_amdgcn_exp2f(s_acc[tn][1]);
      float e2 = __builtin_amdgcn_exp2f(s_acc[tn][2]);
      float e3 = __builtin_amdgcn_exp2f(s_acc[tn][3]);
      l_acc[tn] += (e0 + e1) + (e2 + e3);
      union { u32 u[2]; s16x4 s; } pu;
      pu.u[0] = pk2bf(e0, e1);
      pu.u[1] = pk2bf(e2, e3);
      pf[tn] = pu.s;
    }

    // O^T partial += Vt * P^T over this wave's 16 keys (K=16 MFMA)
    int vcol = w * 16 + quad * 4;
    int vchunk = vcol >> 3, voff = vcol & 7;
#pragma unroll
    for (int tm = 0; tm < 4; tm++) {
      int pp = vchunk ^ rx;
      s16x4 va = *(const s16x4*)&vsb[(tm * 16 + r) * 64 + pp * 8 + voff];
#pragma unroll
      for (int tn = 0; tn < 4; tn++)
        o_acc[tm][tn] = mfma16(va, pf[tn], o_acc[tm][tn]);
    }
  }

  // ---- epilogue: l combine + pairwise cross-wave O reduction via dead staging LDS ----
#pragma unroll
  for (int tn = 0; tn < 4; tn++) {
    l_acc[tn] += __shfl_xor(l_acc[tn], 16);
    l_acc[tn] += __shfl_xor(l_acc[tn], 32);
  }
  if (quad == 0) {
#pragma unroll
    for (int tn = 0; tn < 4; tn++) l_s[w * 64 + tn * 16 + r] = l_acc[tn];
  }
  __syncthreads();  // all waves done with staging + l_s visible
  float* red = (float*)smem;  // 2 slots x 4 tm x 1024 f32 = 32 KB
  if (w & 1) {  // waves 1,3 -> slots 0,1
    int slot = w >> 1;
#pragma unroll
    for (int tm = 0; tm < 4; tm++)
#pragma unroll
      for (int tn = 0; tn < 4; tn++)
        *(f32x4*)&red[slot * 4096 + tm * 1024 + (tn * 16 + r) * 16 + quad * 4] = o_acc[tm][tn];
  }
  __syncthreads();
  if (!(w & 1)) {
    int slot = w >> 1;
#pragma unroll
    for (int tm = 0; tm < 4; tm++)
#pragma unroll
      for (int tn = 0; tn < 4; tn++)
        o_acc[tm][tn] += *(const f32x4*)&red[slot * 4096 + tm * 1024 + (tn * 16 + r) * 16 + quad * 4];
  }
  __syncthreads();
  if (w == 2) {
#pragma unroll
    for (int tm = 0; tm < 4; tm++)
#pragma unroll
      for (int tn = 0; tn < 4; tn++)
        *(f32x4*)&red[tm * 1024 + (tn * 16 + r) * 16 + quad * 4] = o_acc[tm][tn];
  }
  __syncthreads();
  if (w == 0) {
    float inv[4];
#pragma unroll
    for (int tn = 0; tn < 4; tn++) {
      int q = tn * 16 + r;
      inv[tn] = 1.0f / (((l_s[q] + l_s[64 + q]) + (l_s[128 + q] + l_s[192 + q])));
    }
#pragma unroll
    for (int tm = 0; tm < 4; tm++) {
#pragma unroll
      for (int tn = 0; tn < 4; tn++) {
        f32x4 o = o_acc[tm][tn];
        o += *(const f32x4*)&red[tm * 1024 + (tn * 16 + r) * 16 + quad * 4];
        uint2 pk;
        pk.x = pk2bf(o[0] * inv[tn], o[1] * inv[tn]);
        pk.y = pk2bf(o[2] * inv[tn], o[3] * inv[tn]);
        *(uint2*)&O[(size_t)(b * N_L + i0 + tn * 16 + r) * 1024 + h * 64 + tm * 16 + quad * 4] = pk;
      }
    }
  }
}

// ---------------- launch ----------------

extern "C" void kernel_launch(void* const* d_in, const int* in_sizes, int n_in,
                              void* d_out, int out_size, void* d_ws, size_t ws_size,
                              hipStream_t stream) {
  const float* x = (const float*)d_in[0];
  const float* Wq = (const float*)d_in[1];
  const float* Wk = (const float*)d_in[2];
  const float* Wv = (const float*)d_in[3];
  const float* Wo = (const float*)d_in[4];
  float* out = (float*)d_out;
  char* ws = (char*)d_ws;

  u16* xb    = (u16*)(ws);                // 8 MB  [4096][1024]
  u16* wqkvT = (u16*)(ws + 0x800000);     // 3 MB  [1536][1024]
  u16* woT   = (u16*)(ws + 0xB00000);     // 2 MB  [1024][1024]
  u16* Qb    = (u16*)(ws + 0xD00000);     // 8 MB  [B][H][L][64] (pre-scaled QSCALE)
  u16* Kb    = (u16*)(ws + 0x1500000);    // 2 MB  [B][KvH][L][64]
  u16* Vtb   = (u16*)(ws + 0x1700000);    // 2 MB  [B][KvH][64][L]  (transposed)
  u16* Ob    = (u16*)(ws + 0x1900000);    // 8 MB  [4096][1024]
  float* rc  = (float*)(ws + 0x2100000);  // 256 KB [2048][32]
  float* rs  = (float*)(ws + 0x2140000);  // 256 KB

  prep_kernel<<<3840, 256, 0, stream>>>(x, Wq, Wk, Wv, Wo, xb, wqkvT, woT, rc, rs);
  gemm_kernel<0><<<dim3(12, 32), 256, 0, stream>>>(xb, wqkvT, Qb, Kb, Vtb, nullptr, rc, rs);
  attn_kernel<<<dim3(32, 16, 2), 256, 0, stream>>>(Qb, Kb, Vtb, Ob);
  (void)hipMemsetAsync(out, 0, (size_t)4096 * 1024 * 4, stream);
  gemm_kernel<2><<<dim3(8, 32, 2), 256, 0, stream>>>(Ob, woT, nullptr, nullptr, nullptr, out, nullptr, nullptr);
}

// Round 11
// 154.929 us; speedup vs baseline: 1.1770x; 1.1770x over previous
//
#include <hip/hip_runtime.h>

typedef unsigned short u16;
typedef unsigned int u32;
typedef short short8 __attribute__((ext_vector_type(8)));
typedef float f32x4 __attribute__((ext_vector_type(4)));

#define N_B 2
#define N_L 2048
#define N_D 1024
#define N_H 16
#define N_KVH 4
#define HDIM 64
#define WINDOW 1024

// log2(e) folded into Q so softmax can use exp2 directly
#define QSCALE (0.125f * 1.44269504088896f)

__device__ __forceinline__ u16 f2bf(float f) {
  unsigned u = __builtin_bit_cast(unsigned, f);
  u = u + 0x7fffu + ((u >> 16) & 1u);
  return (u16)(u >> 16);
}

// pack two f32 -> (bf16(hi)<<16)|bf16(lo), round-half-up, one v_perm
__device__ __forceinline__ u32 pk2bf(float lo, float hi) {
  u32 a = __builtin_bit_cast(u32, lo) + 0x8000u;
  u32 b = __builtin_bit_cast(u32, hi) + 0x8000u;
  return __builtin_amdgcn_perm(b, a, 0x07060302u);
}

// async global->LDS, 16B per lane. LDS dest must be wave-uniform base + lane*16.
__device__ __forceinline__ void gl2lds16(const u16* g, u16* l) {
  __builtin_amdgcn_global_load_lds((const __attribute__((address_space(1))) void*)g,
                                   (__attribute__((address_space(3))) void*)l, 16, 0, 0);
}

// ---------------- fused prep: convert x, transpose 4 weights, rope ----------------

__global__ __launch_bounds__(256) void prep_kernel(
    const float* __restrict__ x, const float* __restrict__ Wq, const float* __restrict__ Wk,
    const float* __restrict__ Wv, const float* __restrict__ Wo,
    u16* __restrict__ xb, u16* __restrict__ wqkvT, u16* __restrict__ woT,
    float* __restrict__ rc, float* __restrict__ rs) {
  __shared__ float tbuf[32][33];
  int bid = blockIdx.x, tid = threadIdx.x;
  if (bid < 1024) {  // x fp32 -> bf16, 16 elems/thread
    size_t base = ((size_t)bid * 256 + tid) * 16;
    u32 o[8];
#pragma unroll
    for (int j = 0; j < 4; j++) {
      float4 f = *(const float4*)&x[base + j * 4];
      o[2 * j] = pk2bf(f.x, f.y);
      o[2 * j + 1] = pk2bf(f.z, f.w);
    }
    *(uint4*)&xb[base] = *(uint4*)&o[0];
    *(uint4*)&xb[base + 8] = *(uint4*)&o[4];
  } else if (bid < 3584) {  // weight transposes [1024][srcN] -> [srcN][1024] bf16
    const float* src;
    u16* dst;
    int gx, t, shift;
    if (bid < 2048) { src = Wq; dst = wqkvT; gx = 32; shift = 5; t = bid - 1024; }
    else if (bid < 2304) { src = Wk; dst = wqkvT + 1024 * 1024; gx = 8; shift = 3; t = bid - 2048; }
    else if (bid < 2560) { src = Wv; dst = wqkvT + 1280 * 1024; gx = 8; shift = 3; t = bid - 2304; }
    else { src = Wo; dst = woT; gx = 32; shift = 5; t = bid - 2560; }
    int srcN = gx * 32;
    int n0 = (t & (gx - 1)) * 32, k0 = (t >> shift) * 32;
    int lx = tid & 31, ly = tid >> 5;
#pragma unroll
    for (int q = 0; q < 4; q++)
      tbuf[ly + 8 * q][lx] = src[(k0 + ly + 8 * q) * srcN + n0 + lx];
    __syncthreads();
#pragma unroll
    for (int q = 0; q < 4; q++)
      dst[(n0 + ly + 8 * q) * 1024 + k0 + lx] = f2bf(tbuf[lx][ly + 8 * q]);
  } else {  // rope tables, 2048*32
    int idx = (bid - 3584) * 256 + tid;
    int i = idx >> 5, j = idx & 31;
    float inv = powf(10000.0f, -(float)j * (1.0f / 32.0f));
    float ang = (float)i * inv;
    rc[idx] = cosf(ang);
    rs[idx] = sinf(ang);
  }
}

// ---------------- GEMM: C[M,N] = A[M,K=1024] * Bt[N,K=1024]^T ----------------
// 128x128 block, 4 waves 2x2 of 64x64, BK=64, XOR-swizzled LDS, double-buffered
// global_load_lds, single barrier per kt.
// MODE 0: qkv projection; RoPE epilogue; V stored transposed. Grid (12, 32).
// MODE 1: out projection, fp32 store. Grid (8, 32).

template <int MODE>
__global__ __launch_bounds__(256, 2) void gemm_kernel(
    const u16* __restrict__ A, const u16* __restrict__ Bt,
    u16* __restrict__ qo, u16* __restrict__ ko, u16* __restrict__ vo,
    float* __restrict__ fo, const float* __restrict__ rc, const float* __restrict__ rs) {
  __shared__ u16 smem[65536 / 2];  // [A0|A1|B0|B1] each 128x64 u16 (8192)
  int tid = threadIdx.x;
  int w = tid >> 6, lane = tid & 63, quad = lane >> 4, r = lane & 15;
  int rx = r & 7;
  int wm = w >> 1, wn = w & 1;
  int m0 = blockIdx.y * 128, n0 = blockIdx.x * 128;

  f32x4 acc[4][4];
#pragma unroll
  for (int a_ = 0; a_ < 4; a_++)
#pragma unroll
    for (int b_ = 0; b_ < 4; b_++) acc[a_][b_] = {0.f, 0.f, 0.f, 0.f};

  auto stage = [&](int kt, int buf) {
    u16* a_s = smem + buf * 8192;
    u16* b_s = smem + 16384 + buf * 8192;
#pragma unroll
    for (int it = 0; it < 4; ++it) {
      int cc = it * 256 + tid;
      int row = cc >> 3, p = cc & 7, c = p ^ (row & 7);
      gl2lds16(&A[(size_t)(m0 + row) * 1024 + kt * 64 + c * 8], &a_s[cc * 8]);
    }
#pragma unroll
    for (int it = 0; it < 4; ++it) {
      int cc = it * 256 + tid;
      int row = cc >> 3, p = cc & 7, c = p ^ (row & 7);
      gl2lds16(&Bt[(size_t)(n0 + row) * 1024 + kt * 64 + c * 8], &b_s[cc * 8]);
    }
  };

  stage(0, 0);
  for (int kt = 0; kt < 16; ++kt) {
    int buf = kt & 1;
    __syncthreads();  // single barrier per kt: drains this buf's staging
    if (kt + 1 < 16) stage(kt + 1, buf ^ 1);
    u16* a_s = smem + buf * 8192;
    u16* b_s = smem + 16384 + buf * 8192;
#pragma unroll
    for (int ks = 0; ks < 2; ks++) {
      int pc = (ks * 4 + quad) ^ rx;
      short8 af[4], bfr[4];
#pragma unroll
      for (int tm = 0; tm < 4; tm++)
        af[tm] = *(const short8*)&a_s[(wm * 64 + tm * 16 + r) * 64 + pc * 8];
#pragma unroll
      for (int tn = 0; tn < 4; tn++)
        bfr[tn] = *(const short8*)&b_s[(wn * 64 + tn * 16 + r) * 64 + pc * 8];
#pragma unroll
      for (int tm = 0; tm < 4; tm++)
#pragma unroll
        for (int tn = 0; tn < 4; tn++)
          acc[tm][tn] = __builtin_amdgcn_mfma_f32_16x16x32_bf16(af[tm], bfr[tn], acc[tm][tn], 0, 0, 0);
    }
  }

  int nbase = n0 + wn * 64;  // 64-aligned, uniform per wave
  if constexpr (MODE == 0) {
    if (nbase < 1024) {  // Q + RoPE + QSCALE
      int h = nbase >> 6;
#pragma unroll
      for (int tm = 0; tm < 4; tm++) {
#pragma unroll
        for (int reg = 0; reg < 4; reg++) {
          int m = m0 + wm * 64 + tm * 16 + quad * 4 + reg;
          int b = m >> 11, i = m & 2047;
          size_t base = ((size_t)(b * N_H + h) * N_L + i) * HDIM;
#pragma unroll
          for (int tn = 0; tn < 2; tn++) {
            int dlo = tn * 16 + r;
            float c = rc[i * 32 + dlo], s = rs[i * 32 + dlo];
            float vlo = acc[tm][tn][reg], vhi = acc[tm][tn + 2][reg];
            qo[base + dlo] = f2bf((vlo * c - vhi * s) * QSCALE);
            qo[base + dlo + 32] = f2bf((vhi * c + vlo * s) * QSCALE);
          }
        }
      }
    } else if (nbase < 1280) {  // K + RoPE
      int h = (nbase - 1024) >> 6;
#pragma unroll
      for (int tm = 0; tm < 4; tm++) {
#pragma unroll
        for (int reg = 0; reg < 4; reg++) {
          int m = m0 + wm * 64 + tm * 16 + quad * 4 + reg;
          int b = m >> 11, i = m & 2047;
          size_t base = ((size_t)(b * N_KVH + h) * N_L + i) * HDIM;
#pragma unroll
          for (int tn = 0; tn < 2; tn++) {
            int dlo = tn * 16 + r;
            float c = rc[i * 32 + dlo], s = rs[i * 32 + dlo];
            float vlo = acc[tm][tn][reg], vhi = acc[tm][tn + 2][reg];
            ko[base + dlo] = f2bf(vlo * c - vhi * s);
            ko[base + dlo + 32] = f2bf(vhi * c + vlo * s);
          }
        }
      }
    } else {  // V: transpose bounce reusing staging LDS -> Vt[b][hkv][64][2048]
      __syncthreads();
      int hkv = (nbase - 1280) >> 6;
      int bb = (m0 + wm * 64) >> 11;
      int tbase = (m0 + wm * 64) & 2047;
      u16* myvs = smem + w * 4608;  // [64 d][64 tok] stride 72
#pragma unroll
      for (int tm = 0; tm < 4; tm++) {
#pragma unroll
        for (int tn = 0; tn < 4; tn++) {
          uint2 pk;
          pk.x = pk2bf(acc[tm][tn][0], acc[tm][tn][1]);
          pk.y = pk2bf(acc[tm][tn][2], acc[tm][tn][3]);
          *(uint2*)&myvs[(tn * 16 + r) * 72 + tm * 16 + quad * 4] = pk;
        }
      }
      __asm__ volatile("s_waitcnt lgkmcnt(0)" ::: "memory");
      u16* vtb = vo + (size_t)((bb * N_KVH + hkv) * 64) * 2048;
#pragma unroll
      for (int q2 = 0; q2 < 8; ++q2) {
        int flat = q2 * 64 + lane;
        int row = flat >> 3, part = flat & 7;
        uint4 val = *(uint4*)&myvs[row * 72 + part * 8];
        *(uint4*)&vtb[row * 2048 + tbase + part * 8] = val;
      }
    }
  } else {  // MODE 1: fp32 store (quad lanes -> consecutive n, coalesced 64B)
#pragma unroll
    for (int tm = 0; tm < 4; tm++) {
#pragma unroll
      for (int reg = 0; reg < 4; reg++) {
        int m = m0 + wm * 64 + tm * 16 + quad * 4 + reg;
#pragma unroll
        for (int tn = 0; tn < 4; tn++)
          fo[(size_t)m * 1024 + nbase + tn * 16 + r] = acc[tm][tn][reg];
      }
    }
  }
}

// ---------------- flash attention, sliding window, GQA ----------------
// 128 queries per block (two 64-query sets share every staged K/V tile):
// staged-tile traffic halves and each tile's LDS fragment reads feed 2x MFMA
// (20 b128 reads / 32 MFMA = 0.625 vs 1.125). Wave w owns queries w*16..+16 of
// each set. S^T = K*Q^T (key-reduction in-lane), O^T = Vt*P^T; fixed-max softmax
// (p = exp2(s), in-lane l); pt buffer reused sequentially per set (wave-local).
// grid (16 qpairs reversed, 16 heads, 2 batch), 256 threads.

__global__ __launch_bounds__(256) void attn_kernel(
    const u16* __restrict__ Q, const u16* __restrict__ K,
    const u16* __restrict__ Vt, u16* __restrict__ O) {
  __shared__ u16 k_s[2][64 * 64];
  __shared__ u16 v_s[2][64 * 64];
  __shared__ u16 pt[4][16 * 64];
  int tid = threadIdx.x, w = tid >> 6, lane = tid & 63, quad = lane >> 4, r = lane & 15;
  int qp = 15 - blockIdx.x;  // long blocks first
  int h = blockIdx.y, b = blockIdx.z;
  int i0 = qp * 128;
  int hk = h >> 2;
  int rx = r & 7;

  // two query sets: set s covers queries [i0 + s*64, i0 + s*64 + 64)
  short8 qf[2][2];
#pragma unroll
  for (int s = 0; s < 2; s++) {
    const u16* qptr = Q + (size_t)((b * N_H + h) * N_L + i0 + s * 64 + w * 16 + r) * HDIM;
    qf[s][0] = *(const short8*)&qptr[quad * 8];
    qf[s][1] = *(const short8*)&qptr[32 + quad * 8];
  }

  const u16* kbase = K + (size_t)(b * N_KVH + hk) * N_L * HDIM;
  const u16* vtbase = Vt + (size_t)(b * N_KVH + hk) * HDIM * N_L;

  auto stage = [&](int jt, int buf) {
#pragma unroll
    for (int it = 0; it < 2; ++it) {
      int cc = it * 256 + tid;
      int row = cc >> 3, p = cc & 7, c = p ^ (row & 7);
      gl2lds16(&kbase[(size_t)(jt * 64 + row) * 64 + c * 8], &k_s[buf][cc * 8]);
    }
#pragma unroll
    for (int it = 0; it < 2; ++it) {
      int cc = it * 256 + tid;
      int row = cc >> 3, p = cc & 7, c = p ^ (row & 7);
      gl2lds16(&vtbase[(size_t)row * 2048 + jt * 64 + c * 8], &v_s[buf][cc * 8]);
    }
  };

  float l_lane[2] = {0.f, 0.f};
  f32x4 o_acc[2][4];
#pragma unroll
  for (int s = 0; s < 2; s++)
#pragma unroll
    for (int tm = 0; tm < 4; tm++) o_acc[s][tm] = {0.f, 0.f, 0.f, 0.f};

  int jt0 = (i0 >= WINDOW) ? ((i0 - (WINDOW - 1)) >> 6) : 0;
  int nt = (2 * qp + 1) - jt0 + 1;  // through the diagonal tile of set B
  u16* mypt = pt[w];

  stage(jt0, 0);

  for (int t = 0; t < nt; ++t) {
    int jt = jt0 + t, j0 = jt << 6, buf = t & 1;
    __syncthreads();  // drains vmcnt: buf's staging complete
    if (t + 1 < nt) stage(jt + 1, buf ^ 1);

    // K fragments once per tile, shared by both query sets
    short8 kf[2][4];
#pragma unroll
    for (int ks = 0; ks < 2; ks++) {
      int pc = (ks * 4 + quad) ^ rx;
#pragma unroll
      for (int tm = 0; tm < 4; tm++)
        kf[ks][tm] = *(const short8*)&k_s[buf][(tm * 16 + r) * 64 + pc * 8];
    }

#pragma unroll
    for (int s = 0; s < 2; s++) {
      int qw0 = i0 + s * 64 + w * 16;
      int iq = qw0 + r;

      // S^T[j][i]: A = K rows (j), B = Q set s (i)
      f32x4 s_acc[4];
#pragma unroll
      for (int tm = 0; tm < 4; tm++) s_acc[tm] = {0.f, 0.f, 0.f, 0.f};
#pragma unroll
      for (int ks = 0; ks < 2; ks++)
#pragma unroll
        for (int tm = 0; tm < 4; tm++)
          s_acc[tm] = __builtin_amdgcn_mfma_f32_16x16x32_bf16(kf[ks][tm], qf[s][ks], s_acc[tm], 0, 0, 0);

      bool interior = (j0 + 63 <= qw0) && (qw0 + 15 - j0 < WINDOW);
      if (!interior) {
#pragma unroll
        for (int tm = 0; tm < 4; tm++) {
#pragma unroll
          for (int reg = 0; reg < 4; reg++) {
            int j = j0 + tm * 16 + quad * 4 + reg;
            bool ok = (j <= iq) && (iq - j < WINDOW);
            if (!ok) s_acc[tm][reg] = -1e30f;  // exp2 -> 0
          }
        }
      }

      // fixed-max softmax: p = exp2(s), in-lane l accumulation
      float p[4][4];
#pragma unroll
      for (int tm = 0; tm < 4; tm++)
#pragma unroll
        for (int reg = 0; reg < 4; reg++) {
          float e = __builtin_amdgcn_exp2f(s_acc[tm][reg]);
          p[tm][reg] = e;
          l_lane[s] += e;
        }

      // P^T (C-layout) -> pt[i][j] swizzled, wave-local (reused per set;
      // same-wave DS ordering + aliasing keeps set A reads before set B writes)
#pragma unroll
      for (int tm = 0; tm < 4; tm++) {
        uint2 pk;
        pk.x = pk2bf(p[tm][0], p[tm][1]);
        pk.y = pk2bf(p[tm][2], p[tm][3]);
        int c = tm * 2 + (quad >> 1), half = quad & 1;
        int pp = c ^ rx;
        *(uint2*)&mypt[r * 64 + pp * 8 + half * 4] = pk;
      }
      __asm__ volatile("s_waitcnt lgkmcnt(0)" ::: "memory");  // wave-local LDS RAW

      // O^T += Vt * P^T : A = Vt rows (d), B = pt rows (i)
#pragma unroll
      for (int ks = 0; ks < 2; ks++) {
        int pc = (ks * 4 + quad) ^ rx;
        short8 bp = *(const short8*)&mypt[r * 64 + pc * 8];
#pragma unroll
        for (int tm = 0; tm < 4; tm++) {
          short8 av = *(const short8*)&v_s[buf][(tm * 16 + r) * 64 + pc * 8];
          o_acc[s][tm] = __builtin_amdgcn_mfma_f32_16x16x32_bf16(av, bp, o_acc[s][tm], 0, 0, 0);
        }
      }
    }
  }

  // epilogue: per set, combine l across quads, divide, store
#pragma unroll
  for (int s = 0; s < 2; s++) {
    float l = l_lane[s];
    l += __shfl_xor(l, 16);
    l += __shfl_xor(l, 32);
    float inv = 1.0f / l;
    int iq = i0 + s * 64 + w * 16 + r;
    size_t obase = (size_t)(b * N_L + iq) * 1024 + h * 64;
#pragma unroll
    for (int tm = 0; tm < 4; tm++) {
      uint2 pk;
      pk.x = pk2bf(o_acc[s][tm][0] * inv, o_acc[s][tm][1] * inv);
      pk.y = pk2bf(o_acc[s][tm][2] * inv, o_acc[s][tm][3] * inv);
      *(uint2*)&O[obase + tm * 16 + quad * 4] = pk;
    }
  }
}

// ---------------- launch ----------------

extern "C" void kernel_launch(void* const* d_in, const int* in_sizes, int n_in,
                              void* d_out, int out_size, void* d_ws, size_t ws_size,
                              hipStream_t stream) {
  const float* x = (const float*)d_in[0];
  const float* Wq = (const float*)d_in[1];
  const float* Wk = (const float*)d_in[2];
  const float* Wv = (const float*)d_in[3];
  const float* Wo = (const float*)d_in[4];
  float* out = (float*)d_out;
  char* ws = (char*)d_ws;

  u16* xb    = (u16*)(ws);                // 8 MB  [4096][1024]
  u16* wqkvT = (u16*)(ws + 0x800000);     // 3 MB  [1536][1024]
  u16* woT   = (u16*)(ws + 0xB00000);     // 2 MB  [1024][1024]
  u16* Qb    = (u16*)(ws + 0xD00000);     // 8 MB  [B][H][L][64] (pre-scaled QSCALE)
  u16* Kb    = (u16*)(ws + 0x1500000);    // 2 MB  [B][KvH][L][64]
  u16* Vtb   = (u16*)(ws + 0x1700000);    // 2 MB  [B][KvH][64][L]  (transposed)
  u16* Ob    = (u16*)(ws + 0x1900000);    // 8 MB  [4096][1024]
  float* rc  = (float*)(ws + 0x2100000);  // 256 KB [2048][32]
  float* rs  = (float*)(ws + 0x2140000);  // 256 KB

  prep_kernel<<<3840, 256, 0, stream>>>(x, Wq, Wk, Wv, Wo, xb, wqkvT, woT, rc, rs);
  gemm_kernel<0><<<dim3(12, 32), 256, 0, stream>>>(xb, wqkvT, Qb, Kb, Vtb, nullptr, rc, rs);
  attn_kernel<<<dim3(16, 16, 2), 256, 0, stream>>>(Qb, Kb, Vtb, Ob);
  gemm_kernel<1><<<dim3(8, 32), 256, 0, stream>>>(Ob, woT, nullptr, nullptr, nullptr, out, nullptr, nullptr);
}

// Round 12
// 148.167 us; speedup vs baseline: 1.2307x; 1.0456x over previous
//
#include <hip/hip_runtime.h>

typedef unsigned short u16;
typedef unsigned int u32;
typedef short short8 __attribute__((ext_vector_type(8)));
typedef float f32x4 __attribute__((ext_vector_type(4)));

#define N_B 2
#define N_L 2048
#define N_D 1024
#define N_H 16
#define N_KVH 4
#define HDIM 64
#define WINDOW 1024

// log2(e) folded into Q so softmax can use exp2 directly
#define QSCALE (0.125f * 1.44269504088896f)

__device__ __forceinline__ u16 f2bf(float f) {
  unsigned u = __builtin_bit_cast(unsigned, f);
  u = u + 0x7fffu + ((u >> 16) & 1u);
  return (u16)(u >> 16);
}

// pack two f32 -> (bf16(hi)<<16)|bf16(lo), round-half-up, one v_perm
__device__ __forceinline__ u32 pk2bf(float lo, float hi) {
  u32 a = __builtin_bit_cast(u32, lo) + 0x8000u;
  u32 b = __builtin_bit_cast(u32, hi) + 0x8000u;
  return __builtin_amdgcn_perm(b, a, 0x07060302u);
}

// async global->LDS, 16B per lane. LDS dest must be wave-uniform base + lane*16.
__device__ __forceinline__ void gl2lds16(const u16* g, u16* l) {
  __builtin_amdgcn_global_load_lds((const __attribute__((address_space(1))) void*)g,
                                   (__attribute__((address_space(3))) void*)l, 16, 0, 0);
}

// ---------------- fused prep: convert x, transpose 4 weights, rope ----------------

__global__ __launch_bounds__(256) void prep_kernel(
    const float* __restrict__ x, const float* __restrict__ Wq, const float* __restrict__ Wk,
    const float* __restrict__ Wv, const float* __restrict__ Wo,
    u16* __restrict__ xb, u16* __restrict__ wqkvT, u16* __restrict__ woT,
    float* __restrict__ rc, float* __restrict__ rs) {
  __shared__ float tbuf[32][33];
  int bid = blockIdx.x, tid = threadIdx.x;
  if (bid < 1024) {  // x fp32 -> bf16, 16 elems/thread
    size_t base = ((size_t)bid * 256 + tid) * 16;
    u32 o[8];
#pragma unroll
    for (int j = 0; j < 4; j++) {
      float4 f = *(const float4*)&x[base + j * 4];
      o[2 * j] = pk2bf(f.x, f.y);
      o[2 * j + 1] = pk2bf(f.z, f.w);
    }
    *(uint4*)&xb[base] = *(uint4*)&o[0];
    *(uint4*)&xb[base + 8] = *(uint4*)&o[4];
  } else if (bid < 3584) {  // weight transposes [1024][srcN] -> [srcN][1024] bf16
    const float* src;
    u16* dst;
    int gx, t, shift;
    if (bid < 2048) { src = Wq; dst = wqkvT; gx = 32; shift = 5; t = bid - 1024; }
    else if (bid < 2304) { src = Wk; dst = wqkvT + 1024 * 1024; gx = 8; shift = 3; t = bid - 2048; }
    else if (bid < 2560) { src = Wv; dst = wqkvT + 1280 * 1024; gx = 8; shift = 3; t = bid - 2304; }
    else { src = Wo; dst = woT; gx = 32; shift = 5; t = bid - 2560; }
    int srcN = gx * 32;
    int n0 = (t & (gx - 1)) * 32, k0 = (t >> shift) * 32;
    int lx = tid & 31, ly = tid >> 5;
#pragma unroll
    for (int q = 0; q < 4; q++)
      tbuf[ly + 8 * q][lx] = src[(k0 + ly + 8 * q) * srcN + n0 + lx];
    __syncthreads();
#pragma unroll
    for (int q = 0; q < 4; q++)
      dst[(n0 + ly + 8 * q) * 1024 + k0 + lx] = f2bf(tbuf[lx][ly + 8 * q]);
  } else {  // rope tables, 2048*32
    int idx = (bid - 3584) * 256 + tid;
    int i = idx >> 5, j = idx & 31;
    float inv = powf(10000.0f, -(float)j * (1.0f / 32.0f));
    float ang = (float)i * inv;
    rc[idx] = cosf(ang);
    rs[idx] = sinf(ang);
  }
}

// ---------------- GEMM: C[M,N] = A[M,K=1024] * Bt[N,K=1024]^T ----------------
// 128x128 block, 4 waves 2x2 of 64x64, BK=64, XOR-swizzled LDS, double-buffered
// global_load_lds, single barrier per kt.
// MODE 0: qkv projection; RoPE epilogue; V stored transposed. Grid (12, 32).
// MODE 1: out projection, fp32 store. Grid (8, 32).

template <int MODE>
__global__ __launch_bounds__(256, 2) void gemm_kernel(
    const u16* __restrict__ A, const u16* __restrict__ Bt,
    u16* __restrict__ qo, u16* __restrict__ ko, u16* __restrict__ vo,
    float* __restrict__ fo, const float* __restrict__ rc, const float* __restrict__ rs) {
  __shared__ u16 smem[65536 / 2];  // [A0|A1|B0|B1] each 128x64 u16 (8192)
  int tid = threadIdx.x;
  int w = tid >> 6, lane = tid & 63, quad = lane >> 4, r = lane & 15;
  int rx = r & 7;
  int wm = w >> 1, wn = w & 1;
  int m0 = blockIdx.y * 128, n0 = blockIdx.x * 128;

  f32x4 acc[4][4];
#pragma unroll
  for (int a_ = 0; a_ < 4; a_++)
#pragma unroll
    for (int b_ = 0; b_ < 4; b_++) acc[a_][b_] = {0.f, 0.f, 0.f, 0.f};

  auto stage = [&](int kt, int buf) {
    u16* a_s = smem + buf * 8192;
    u16* b_s = smem + 16384 + buf * 8192;
#pragma unroll
    for (int it = 0; it < 4; ++it) {
      int cc = it * 256 + tid;
      int row = cc >> 3, p = cc & 7, c = p ^ (row & 7);
      gl2lds16(&A[(size_t)(m0 + row) * 1024 + kt * 64 + c * 8], &a_s[cc * 8]);
    }
#pragma unroll
    for (int it = 0; it < 4; ++it) {
      int cc = it * 256 + tid;
      int row = cc >> 3, p = cc & 7, c = p ^ (row & 7);
      gl2lds16(&Bt[(size_t)(n0 + row) * 1024 + kt * 64 + c * 8], &b_s[cc * 8]);
    }
  };

  stage(0, 0);
  for (int kt = 0; kt < 16; ++kt) {
    int buf = kt & 1;
    __syncthreads();  // single barrier per kt: drains this buf's staging
    if (kt + 1 < 16) stage(kt + 1, buf ^ 1);
    u16* a_s = smem + buf * 8192;
    u16* b_s = smem + 16384 + buf * 8192;
#pragma unroll
    for (int ks = 0; ks < 2; ks++) {
      int pc = (ks * 4 + quad) ^ rx;
      short8 af[4], bfr[4];
#pragma unroll
      for (int tm = 0; tm < 4; tm++)
        af[tm] = *(const short8*)&a_s[(wm * 64 + tm * 16 + r) * 64 + pc * 8];
#pragma unroll
      for (int tn = 0; tn < 4; tn++)
        bfr[tn] = *(const short8*)&b_s[(wn * 64 + tn * 16 + r) * 64 + pc * 8];
#pragma unroll
      for (int tm = 0; tm < 4; tm++)
#pragma unroll
        for (int tn = 0; tn < 4; tn++)
          acc[tm][tn] = __builtin_amdgcn_mfma_f32_16x16x32_bf16(af[tm], bfr[tn], acc[tm][tn], 0, 0, 0);
    }
  }

  int nbase = n0 + wn * 64;  // 64-aligned, uniform per wave
  if constexpr (MODE == 0) {
    if (nbase < 1024) {  // Q + RoPE + QSCALE
      int h = nbase >> 6;
#pragma unroll
      for (int tm = 0; tm < 4; tm++) {
#pragma unroll
        for (int reg = 0; reg < 4; reg++) {
          int m = m0 + wm * 64 + tm * 16 + quad * 4 + reg;
          int b = m >> 11, i = m & 2047;
          size_t base = ((size_t)(b * N_H + h) * N_L + i) * HDIM;
#pragma unroll
          for (int tn = 0; tn < 2; tn++) {
            int dlo = tn * 16 + r;
            float c = rc[i * 32 + dlo], s = rs[i * 32 + dlo];
            float vlo = acc[tm][tn][reg], vhi = acc[tm][tn + 2][reg];
            qo[base + dlo] = f2bf((vlo * c - vhi * s) * QSCALE);
            qo[base + dlo + 32] = f2bf((vhi * c + vlo * s) * QSCALE);
          }
        }
      }
    } else if (nbase < 1280) {  // K + RoPE
      int h = (nbase - 1024) >> 6;
#pragma unroll
      for (int tm = 0; tm < 4; tm++) {
#pragma unroll
        for (int reg = 0; reg < 4; reg++) {
          int m = m0 + wm * 64 + tm * 16 + quad * 4 + reg;
          int b = m >> 11, i = m & 2047;
          size_t base = ((size_t)(b * N_KVH + h) * N_L + i) * HDIM;
#pragma unroll
          for (int tn = 0; tn < 2; tn++) {
            int dlo = tn * 16 + r;
            float c = rc[i * 32 + dlo], s = rs[i * 32 + dlo];
            float vlo = acc[tm][tn][reg], vhi = acc[tm][tn + 2][reg];
            ko[base + dlo] = f2bf(vlo * c - vhi * s);
            ko[base + dlo + 32] = f2bf(vhi * c + vlo * s);
          }
        }
      }
    } else {  // V: transpose bounce reusing staging LDS -> Vt[b][hkv][64][2048]
      __syncthreads();
      int hkv = (nbase - 1280) >> 6;
      int bb = (m0 + wm * 64) >> 11;
      int tbase = (m0 + wm * 64) & 2047;
      u16* myvs = smem + w * 4608;  // [64 d][64 tok] stride 72
#pragma unroll
      for (int tm = 0; tm < 4; tm++) {
#pragma unroll
        for (int tn = 0; tn < 4; tn++) {
          uint2 pk;
          pk.x = pk2bf(acc[tm][tn][0], acc[tm][tn][1]);
          pk.y = pk2bf(acc[tm][tn][2], acc[tm][tn][3]);
          *(uint2*)&myvs[(tn * 16 + r) * 72 + tm * 16 + quad * 4] = pk;
        }
      }
      __asm__ volatile("s_waitcnt lgkmcnt(0)" ::: "memory");
      u16* vtb = vo + (size_t)((bb * N_KVH + hkv) * 64) * 2048;
#pragma unroll
      for (int q2 = 0; q2 < 8; ++q2) {
        int flat = q2 * 64 + lane;
        int row = flat >> 3, part = flat & 7;
        uint4 val = *(uint4*)&myvs[row * 72 + part * 8];
        *(uint4*)&vtb[row * 2048 + tbase + part * 8] = val;
      }
    }
  } else {  // MODE 1: fp32 store (quad lanes -> consecutive n, coalesced 64B)
#pragma unroll
    for (int tm = 0; tm < 4; tm++) {
#pragma unroll
      for (int reg = 0; reg < 4; reg++) {
        int m = m0 + wm * 64 + tm * 16 + quad * 4 + reg;
#pragma unroll
        for (int tn = 0; tn < 4; tn++)
          fo[(size_t)m * 1024 + nbase + tn * 16 + r] = acc[tm][tn][reg];
      }
    }
  }
}

// ---------------- flash attention, sliding window, GQA ----------------
// S^T = K*Q^T (key-reduction in-lane), O^T = Vt*P^T.
// Fixed-max softmax: p = exp2(s); l accumulated in-lane AFTER the pt-write issue
// so the 16 VALU adds execute in the lgkmcnt-drain shadow.
// XOR-swizzled LDS, double-buffered K/V staging, one barrier per tile.
// grid (32 qblocks reversed, 16 heads, 2 batch), 256 threads (4 waves x 16 q).

__global__ __launch_bounds__(256) void attn_kernel(
    const u16* __restrict__ Q, const u16* __restrict__ K,
    const u16* __restrict__ Vt, u16* __restrict__ O) {
  __shared__ u16 k_s[2][64 * 64];
  __shared__ u16 v_s[2][64 * 64];
  __shared__ u16 pt[4][16 * 64];
  int tid = threadIdx.x, w = tid >> 6, lane = tid & 63, quad = lane >> 4, r = lane & 15;
  int qb = 31 - blockIdx.x;  // long blocks first
  int h = blockIdx.y, b = blockIdx.z;
  int i0 = qb * 64;
  int hk = h >> 2;
  int qw0 = i0 + w * 16;
  int iq = qw0 + r;

  const u16* qptr = Q + (size_t)((b * N_H + h) * N_L + iq) * HDIM;
  short8 qf[2];
  qf[0] = *(const short8*)&qptr[quad * 8];
  qf[1] = *(const short8*)&qptr[32 + quad * 8];

  const u16* kbase = K + (size_t)(b * N_KVH + hk) * N_L * HDIM;
  const u16* vtbase = Vt + (size_t)(b * N_KVH + hk) * HDIM * N_L;

  auto stage = [&](int jt, int buf) {
#pragma unroll
    for (int it = 0; it < 2; ++it) {
      int cc = it * 256 + tid;
      int row = cc >> 3, p = cc & 7, c = p ^ (row & 7);
      gl2lds16(&kbase[(size_t)(jt * 64 + row) * 64 + c * 8], &k_s[buf][cc * 8]);
    }
#pragma unroll
    for (int it = 0; it < 2; ++it) {
      int cc = it * 256 + tid;
      int row = cc >> 3, p = cc & 7, c = p ^ (row & 7);
      gl2lds16(&vtbase[(size_t)row * 2048 + jt * 64 + c * 8], &v_s[buf][cc * 8]);
    }
  };

  float l_lane = 0.f;
  f32x4 o_acc[4];
#pragma unroll
  for (int tm = 0; tm < 4; tm++) o_acc[tm] = {0.f, 0.f, 0.f, 0.f};

  int jt0 = (i0 >= WINDOW) ? ((i0 - (WINDOW - 1)) >> 6) : 0;
  int nt = qb - jt0 + 1;
  u16* mypt = pt[w];
  int rx = r & 7;

  stage(jt0, 0);

  for (int t = 0; t < nt; ++t) {
    int jt = jt0 + t, j0 = jt << 6, buf = t & 1;
    __syncthreads();  // drains vmcnt: buf's staging complete
    if (t + 1 < nt) stage(jt + 1, buf ^ 1);

    // S^T[j][i]: A = K rows (j), B = Q (i)
    f32x4 s_acc[4];
#pragma unroll
    for (int tm = 0; tm < 4; tm++) s_acc[tm] = {0.f, 0.f, 0.f, 0.f};
#pragma unroll
    for (int ks = 0; ks < 2; ks++) {
      int pc = (ks * 4 + quad) ^ rx;
#pragma unroll
      for (int tm = 0; tm < 4; tm++) {
        short8 kf = *(const short8*)&k_s[buf][(tm * 16 + r) * 64 + pc * 8];
        s_acc[tm] = __builtin_amdgcn_mfma_f32_16x16x32_bf16(kf, qf[ks], s_acc[tm], 0, 0, 0);
      }
    }

    bool interior = (j0 + 63 <= qw0) && (qw0 + 15 - j0 < WINDOW);
    if (!interior) {
#pragma unroll
      for (int tm = 0; tm < 4; tm++) {
#pragma unroll
        for (int reg = 0; reg < 4; reg++) {
          int j = j0 + tm * 16 + quad * 4 + reg;
          bool ok = (j <= iq) && (iq - j < WINDOW);
          if (!ok) s_acc[tm][reg] = -1e30f;  // exp2 -> 0
        }
      }
    }

    // fixed-max softmax: p = exp2(s); pack + write pt FIRST, l-adds in the
    // drain shadow afterwards
    float p[4][4];
#pragma unroll
    for (int tm = 0; tm < 4; tm++)
#pragma unroll
      for (int reg = 0; reg < 4; reg++)
        p[tm][reg] = __builtin_amdgcn_exp2f(s_acc[tm][reg]);

    // P^T (C-layout) -> pt[i][j] swizzled, wave-local
#pragma unroll
    for (int tm = 0; tm < 4; tm++) {
      uint2 pk;
      pk.x = pk2bf(p[tm][0], p[tm][1]);
      pk.y = pk2bf(p[tm][2], p[tm][3]);
      int c = tm * 2 + (quad >> 1), half = quad & 1;
      int pp = c ^ rx;
      *(uint2*)&mypt[r * 64 + pp * 8 + half * 4] = pk;
    }

    // l accumulation hides in the LDS-write drain
#pragma unroll
    for (int tm = 0; tm < 4; tm++)
      l_lane += ((p[tm][0] + p[tm][1]) + (p[tm][2] + p[tm][3]));

    __asm__ volatile("s_waitcnt lgkmcnt(0)" ::: "memory");  // wave-local LDS RAW

    // O^T += Vt * P^T : A = Vt rows (d), B = pt rows (i)
#pragma unroll
    for (int ks = 0; ks < 2; ks++) {
      int pc = (ks * 4 + quad) ^ rx;
      short8 bp = *(const short8*)&mypt[r * 64 + pc * 8];
#pragma unroll
      for (int tm = 0; tm < 4; tm++) {
        short8 av = *(const short8*)&v_s[buf][(tm * 16 + r) * 64 + pc * 8];
        o_acc[tm] = __builtin_amdgcn_mfma_f32_16x16x32_bf16(av, bp, o_acc[tm], 0, 0, 0);
      }
    }
  }

  // epilogue: combine l across quads (once), divide, store
  l_lane += __shfl_xor(l_lane, 16);
  l_lane += __shfl_xor(l_lane, 32);
  float inv = 1.0f / l_lane;
  size_t obase = (size_t)(b * N_L + iq) * 1024 + h * 64;
#pragma unroll
  for (int tm = 0; tm < 4; tm++) {
    uint2 pk;
    pk.x = pk2bf(o_acc[tm][0] * inv, o_acc[tm][1] * inv);
    pk.y = pk2bf(o_acc[tm][2] * inv, o_acc[tm][3] * inv);
    *(uint2*)&O[obase + tm * 16 + quad * 4] = pk;
  }
}

// ---------------- launch ----------------

extern "C" void kernel_launch(void* const* d_in, const int* in_sizes, int n_in,
                              void* d_out, int out_size, void* d_ws, size_t ws_size,
                              hipStream_t stream) {
  const float* x = (const float*)d_in[0];
  const float* Wq = (const float*)d_in[1];
  const float* Wk = (const float*)d_in[2];
  const float* Wv = (const float*)d_in[3];
  const float* Wo = (const float*)d_in[4];
  float* out = (float*)d_out;
  char* ws = (char*)d_ws;

  u16* xb    = (u16*)(ws);                // 8 MB  [4096][1024]
  u16* wqkvT = (u16*)(ws + 0x800000);     // 3 MB  [1536][1024]
  u16* woT   = (u16*)(ws + 0xB00000);     // 2 MB  [1024][1024]
  u16* Qb    = (u16*)(ws + 0xD00000);     // 8 MB  [B][H][L][64] (pre-scaled QSCALE)
  u16* Kb    = (u16*)(ws + 0x1500000);    // 2 MB  [B][KvH][L][64]
  u16* Vtb   = (u16*)(ws + 0x1700000);    // 2 MB  [B][KvH][64][L]  (transposed)
  u16* Ob    = (u16*)(ws + 0x1900000);    // 8 MB  [4096][1024]
  float* rc  = (float*)(ws + 0x2100000);  // 256 KB [2048][32]
  float* rs  = (float*)(ws + 0x2140000);  // 256 KB

  prep_kernel<<<3840, 256, 0, stream>>>(x, Wq, Wk, Wv, Wo, xb, wqkvT, woT, rc, rs);
  gemm_kernel<0><<<dim3(12, 32), 256, 0, stream>>>(xb, wqkvT, Qb, Kb, Vtb, nullptr, rc, rs);
  attn_kernel<<<dim3(32, 16, 2), 256, 0, stream>>>(Qb, Kb, Vtb, Ob);
  gemm_kernel<1><<<dim3(8, 32), 256, 0, stream>>>(Ob, woT, nullptr, nullptr, nullptr, out, nullptr, nullptr);
}